// Round 13
// baseline (154.366 us; speedup 1.0000x reference)
//
#include <hip/hip_runtime.h>
#include <hip/hip_bf16.h>
#include <stdint.h>

// Problem constants
#define BB 2
#define NN 2048
#define DD 512
#define HH 8
#define DHH 64
// bh count = 16, per-head Q/K/V = 2048*64 elems = 131072

typedef __attribute__((ext_vector_type(8))) short bf16x8;   // 8 bf16 = 4 VGPR
typedef __attribute__((ext_vector_type(4))) float f32x4;    // MFMA C/D frag

#define LOG2E 1.44269504088896340736f

#if __has_builtin(__builtin_amdgcn_exp2f)
#define QSCALE (0.125f * LOG2E)
#define EXP2(x) __builtin_amdgcn_exp2f(x)
#else
#define QSCALE 0.125f
#define EXP2(x) __expf(x)
#endif

static __device__ __forceinline__ unsigned short f2bf(float f) {
    union { float f; unsigned u; } v; v.f = f;
    unsigned r = v.u + 0x7fffu + ((v.u >> 16) & 1u);  // RNE
    return (unsigned short)(r >> 16);
}

// pack two floats -> bf16 pair, COMPILER-VISIBLE (emits v_cvt_pk_bf16_f32)
static __device__ __forceinline__ unsigned pk2(float a, float b) {
    __hip_bfloat162 h = __float22bfloat162_rn(make_float2(a, b));
    union { __hip_bfloat162 h; unsigned u; } cv; cv.h = h;
    return cv.u;
}

static __device__ __forceinline__ bf16x8 ld8(const unsigned short* p) {
    bf16x8 v; __builtin_memcpy(&v, p, 16); return v;
}

// async global->LDS, 16B per lane; LDS dest = wave-uniform base + lane*16
static __device__ __forceinline__ void gld_lds16(const void* g, void* l) {
    __builtin_amdgcn_global_load_lds((const __attribute__((address_space(1))) void*)g,
                                     (__attribute__((address_space(3))) void*)l, 16, 0, 0);
}

// ---------------- prep: transpose-cast Wq/Wk/Wv only (x-cast deleted; Wo on flash) --
__global__ void ca_prep(const float* __restrict__ w0, const float* __restrict__ w1,
                        const float* __restrict__ w2,
                        unsigned short* __restrict__ wts) {
    __shared__ float T[64][65];
    int bb = blockIdx.x;
    int z = bb >> 6, t = bb & 63;
    const float* W = (z == 0) ? w0 : (z == 1) ? w1 : w2;
    unsigned short* out = wts + z * 262144;
    int k0 = (t & 7) << 6, n0 = (t >> 3) << 6;
    int c = threadIdx.x & 63, r4 = threadIdx.x >> 6;
#pragma unroll
    for (int rr = 0; rr < 16; ++rr) {
        int r = r4 * 16 + rr;
        T[r][c] = W[(k0 + r) * 512 + n0 + c];
    }
    __syncthreads();
#pragma unroll
    for (int rr = 0; rr < 16; ++rr) {
        int r = r4 * 16 + rr;
        out[(n0 + r) * 512 + k0 + c] = f2bf(T[c][r]);
    }
}

// ------------- QKV projection GEMM v5: A self-staged from f32 x (xb deleted) --------
// grid (32, 24): by>>3 = z (0=Q,1=K,2=V), (by&7)*64 = n0.
// A: R11-proven path — coalesced float4 loads -> cvt_pk -> swizzled ds_write_b128
//    (single Ash buffer). B: R9-proven dbuf gld_lds16 from pre-transposed bf16 wts.
// Per iter k: vmcnt(0) [A regs + B LDS landed] -> barrier1 [Ash & Bsh[b^1] free]
// -> cvt+write A -> issue B(k+1)->Bsh[b^1] + A(k+1) f32 loads -> barrier2 [Ash ready]
// -> ds_read frags from Ash/Bsh[b] -> MFMA. Epilogue identical to R9.
__global__ __launch_bounds__(256, 3)
void ca_gemm_proj(const float* __restrict__ x,
                  const unsigned short* __restrict__ wts,
                  unsigned short* __restrict__ qkv,
                  unsigned short* __restrict__ vt) {
    __shared__ __align__(16) unsigned short Ash[128 * 64];
    __shared__ __align__(16) unsigned short Bsh[2][64 * 64];
    int z = blockIdx.y >> 3;
    const unsigned short* BT = wts + z * 262144;
    unsigned short* out = qkv + z * 2097152;
    int tid = threadIdx.x;
    int w = tid >> 6, lane = tid & 63;
    int c = lane & 15, qd = lane >> 4;
    int m0 = blockIdx.x * 128 + w * 16;          // wave covers m0 and m0+64
    int n0 = (blockIdx.y & 7) * 64;

    // A staging: rowA = tid>>1 (0..127), half ha = tid&1 (k-cols ha*32..+31)
    int rowA = tid >> 1, ha = tid & 1;
    const float* xA = x + (blockIdx.x * 128 + rowA) * 512 + ha * 32;
    // B staging (gld_lds16): lane -> row lr, slot ls; LDS slot ls holds global ls^(row&7)
    int lr = lane >> 3, ls = lane & 7;
    int soff = lr * 512 + ((ls ^ (lr & 7)) << 3);
    const unsigned short* Bb = BT + n0 * 512 + soff;

    // prologue: B(0) -> Bsh[0]; A(0) -> regs
#pragma unroll
    for (int L = 0; L < 2; ++L)
        gld_lds16(Bb + (w * 16 + L * 8) * 512, (char*)Bsh[0] + (w * 16 + L * 8) * 128);
    float4 fA4[8];
#pragma unroll
    for (int j = 0; j < 8; ++j) fA4[j] = *(const float4*)(xA + j * 4);

    f32x4 acc[2][4];
#pragma unroll
    for (int mt = 0; mt < 2; ++mt)
#pragma unroll
        for (int nb = 0; nb < 4; ++nb) acc[mt][nb] = (f32x4){0.f, 0.f, 0.f, 0.f};

    int cs = c & 7;
    int ra7 = rowA & 7;
    for (int k = 0; k < 8; ++k) {
        int b = k & 1;
        asm volatile("s_waitcnt vmcnt(0)" ::: "memory");   // A(k) regs + B(k) LDS landed
        __syncthreads();                                   // Ash & Bsh[b^1] reads done
        // cvt + swizzled A write: slots ha*4+q, phys = slot ^ (rowA&7)
#pragma unroll
        for (int q = 0; q < 4; ++q) {
            uint4 pkk;
            pkk.x = pk2(fA4[q * 2].x, fA4[q * 2].y);
            pkk.y = pk2(fA4[q * 2].z, fA4[q * 2].w);
            pkk.z = pk2(fA4[q * 2 + 1].x, fA4[q * 2 + 1].y);
            pkk.w = pk2(fA4[q * 2 + 1].z, fA4[q * 2 + 1].w);
            int sl = (ha * 4 + q) ^ ra7;
            *(uint4*)((char*)Ash + rowA * 128 + sl * 16) = pkk;
        }
        // issue next chunk's loads (after barrier1: Bsh[b^1] free; fA4 consumed by cvt)
        if (k < 7) {
            int k0n = (k + 1) * 64;
#pragma unroll
            for (int L = 0; L < 2; ++L)
                gld_lds16(Bb + k0n + (w * 16 + L * 8) * 512,
                          (char*)Bsh[b ^ 1] + (w * 16 + L * 8) * 128);
#pragma unroll
            for (int j = 0; j < 8; ++j) fA4[j] = *(const float4*)(xA + k0n + j * 4);
        }
        __syncthreads();                                   // Ash writes visible
        bf16x8 a[2][2], bq[4][2];
#pragma unroll
        for (int mt = 0; mt < 2; ++mt)
#pragma unroll
            for (int kk = 0; kk < 2; ++kk)
                a[mt][kk] = ld8((const unsigned short*)((char*)Ash +
                                (w * 16 + mt * 64 + c) * 128 + (((kk * 4 + qd) ^ cs) << 4)));
#pragma unroll
        for (int nb = 0; nb < 4; ++nb)
#pragma unroll
            for (int kk = 0; kk < 2; ++kk)
                bq[nb][kk] = ld8((const unsigned short*)((char*)Bsh[b] +
                                (nb * 16 + c) * 128 + (((kk * 4 + qd) ^ cs) << 4)));
#pragma unroll
        for (int kk = 0; kk < 2; ++kk)
#pragma unroll
            for (int nb = 0; nb < 4; ++nb) {
                acc[0][nb] = __builtin_amdgcn_mfma_f32_16x16x32_bf16(a[0][kk], bq[nb][kk], acc[0][nb], 0, 0, 0);
                acc[1][nb] = __builtin_amdgcn_mfma_f32_16x16x32_bf16(a[1][kk], bq[nb][kk], acc[1][nb], 0, 0, 0);
            }
    }

    if (z == 2) {
        // V: write transposed [bh][d][i], 4 consecutive i packed per store
#pragma unroll
        for (int mt = 0; mt < 2; ++mt) {
            int ib = m0 + mt * 64 + qd * 4;      // i base (4-aligned)
            int b = ib >> 11, i = ib & 2047;
#pragma unroll
            for (int nb = 0; nb < 4; ++nb) {
                int col = n0 + nb * 16 + c;      // h*64 + d
                int h = col >> 6, d = col & 63;
                ushort4 pk;
                pk.x = f2bf(acc[mt][nb][0]); pk.y = f2bf(acc[mt][nb][1]);
                pk.z = f2bf(acc[mt][nb][2]); pk.w = f2bf(acc[mt][nb][3]);
                *(ushort4*)(vt + (((b << 3) + h) * 64 + d) * 2048 + i) = pk;
            }
        }
    } else {
        float scale = (z == 0) ? QSCALE : 1.0f;
#pragma unroll
        for (int mt = 0; mt < 2; ++mt)
#pragma unroll
            for (int nb = 0; nb < 4; ++nb) {
#pragma unroll
                for (int r = 0; r < 4; ++r) {
                    int row = m0 + mt * 64 + qd * 4 + r;
                    int col = n0 + nb * 16 + c;
                    int b = row >> 11, i = row & 2047, h = col >> 6, d = col & 63;
                    out[(((b << 3) + h) * 2048 + i) * 64 + d] = f2bf(acc[mt][nb][r] * scale);
                }
            }
    }
}

// ------------- Flash attention v11: float4 pair-table (1 gather, not 2) -------------
// lrg4[130] float4: entry d = (rel[d],gate[d],rel[min(d+1,128)],gate[min(d+1,128)]);
// entry 129 = (rel[0],gate[0],rel[0],gate[0]) for the both-low-clamped case.
// idx = im1 < -64 ? 129 : min(im1,64)+64; one aligned ds_read_b128 per (qt,r).
// Rest of body = R12 (hoisted QK + setprio + split vmcnt + Wo rider).
__global__ __launch_bounds__(256, 4)
void ca_flash(const unsigned short* __restrict__ Q,
              const unsigned short* __restrict__ K,
              const unsigned short* __restrict__ VT,
              const float* __restrict__ rel_pos,
              const float* __restrict__ c_emb,
              unsigned short* __restrict__ Ob,
              const float* __restrict__ Wo,
              unsigned short* __restrict__ woT) {
    __shared__ __align__(16) char smem[38944];

    if (blockIdx.x < 64) {
        // ---- Wo transpose-cast rider ----
        float (*T)[65] = (float (*)[65])smem;     // 16.6KB < 38.9KB
        int t = blockIdx.x;
        int k0 = (t & 7) << 6, n0 = (t >> 3) << 6;
        int c = threadIdx.x & 63, r4 = threadIdx.x >> 6;
#pragma unroll
        for (int rr = 0; rr < 16; ++rr) {
            int r = r4 * 16 + rr;
            T[r][c] = Wo[(k0 + r) * 512 + n0 + c];
        }
        __syncthreads();
#pragma unroll
        for (int rr = 0; rr < 16; ++rr) {
            int r = r4 * 16 + rr;
            woT[(n0 + r) * 512 + k0 + c] = f2bf(T[c][r]);
        }
        return;
    }

    unsigned (*Ptu)[16][16] = (unsigned (*)[16][16])(smem + 32768);
    float* red = (float*)smem;                       // [3][64][41] floats
    float4* lrg4 = (float4*)(smem + 36864);          // 130 pair-entries

    int bx = blockIdx.x - 64;
    int xcd = bx & 7, slot = bx >> 3;           // slot 0..127
    int bh = xcd + ((slot >> 6) << 3);          // heads {xcd, xcd+8} per XCD
    int it = slot & 63;
    int b = bh >> 3, h = bh & 7;
    int w = threadIdx.x >> 6, lane = threadIdx.x & 63;
    int c = lane & 15, qd = lane >> 4;
    int i0 = it * 32;

    if (threadIdx.x < 130) {
        int e1 = (threadIdx.x < 129) ? threadIdx.x : 0;
        int e2 = (threadIdx.x < 129) ? ((threadIdx.x < 128) ? threadIdx.x + 1 : 128) : 0;
        float4 v;
        v.x = rel_pos[e1 * 8 + h] * QSCALE; v.y = c_emb[e1 * 8 + h];
        v.z = rel_pos[e2 * 8 + h] * QSCALE; v.w = c_emb[e2 * 8 + h];
        lrg4[threadIdx.x] = v;
    }

    const unsigned short* Qh = Q  + bh * 131072;
    const unsigned short* Kh = K  + bh * 131072;
    const unsigned short* Vh = VT + bh * 131072;
    char* kw = smem + w * 4096;                 // wave-private K slab (32 rows x 128B)
    char* vw = smem + 16384 + w * 4096;         // wave-private V slab (64 rows x 64B)

    int koff[4], voff[4];
#pragma unroll
    for (int L = 0; L < 4; ++L) {
        int kr = L * 8 + (lane >> 3);
        koff[L] = kr * 64 + (((lane & 7) ^ ((kr >> 1) & 7)) << 3);
        int vr = L * 16 + (lane >> 2);
        voff[L] = vr * 2048 + (((lane & 3) ^ ((lane >> 3) & 3)) << 3);
    }

    // prologue: stage tile t=0 (j0 = w*32): K first, then V (vmcnt(4) split)
    {
        int j0 = w * 32;
#pragma unroll
        for (int L = 0; L < 4; ++L) gld_lds16(Kh + j0 * 64 + koff[L], kw + L * 1024);
#pragma unroll
        for (int L = 0; L < 4; ++L) gld_lds16(Vh + j0 + voff[L], vw + L * 1024);
    }

    bf16x8 aq[2][2];
#pragma unroll
    for (int qt = 0; qt < 2; ++qt) {
        aq[qt][0] = ld8(Qh + (i0 + qt * 16 + c) * 64 + qd * 8);
        aq[qt][1] = ld8(Qh + (i0 + qt * 16 + c) * 64 + 32 + qd * 8);
    }

    f32x4 o2[2][4];
    float lp2[2][4];
#pragma unroll
    for (int qt = 0; qt < 2; ++qt)
#pragma unroll
        for (int db = 0; db < 4; ++db) {
            o2[qt][db] = (f32x4){0.f, 0.f, 0.f, 0.f};
            lp2[qt][db] = 0.f;
        }

    __syncthreads();   // lrg4 ready (also drains prologue stage - harmless)

    int ksw  = c & 7;          // (row>>1)&7 for K rows 2c, 2c+1
    int vsw  = (c >> 1) & 3;   // (row>>1)&3 for V rows db*16+c

    for (int t = 0; t < 16; ++t) {
        asm volatile("s_waitcnt vmcnt(4)" ::: "memory");
        __builtin_amdgcn_sched_barrier(0);
        bf16x8 bk0a = ld8((const unsigned short*)(kw + (2 * c) * 128     + (((qd)     ^ ksw) << 4)));
        bf16x8 bk0b = ld8((const unsigned short*)(kw + (2 * c) * 128     + (((qd + 4) ^ ksw) << 4)));
        bf16x8 bk1a = ld8((const unsigned short*)(kw + (2 * c + 1) * 128 + (((qd)     ^ ksw) << 4)));
        bf16x8 bk1b = ld8((const unsigned short*)(kw + (2 * c + 1) * 128 + (((qd + 4) ^ ksw) << 4)));
        asm volatile("s_waitcnt vmcnt(0)" ::: "memory");
        __builtin_amdgcn_sched_barrier(0);
        bf16x8 bv[4];
#pragma unroll
        for (int db = 0; db < 4; ++db)
            bv[db] = ld8((const unsigned short*)(vw + (db * 16 + c) * 64 + ((qd ^ vsw) << 4)));
        asm volatile("s_waitcnt lgkmcnt(0)" ::: "memory");
        __builtin_amdgcn_sched_barrier(0);
        if (t < 15) {
            int j0n = ((t + 1) * 4 + w) * 32;
#pragma unroll
            for (int L = 0; L < 4; ++L) gld_lds16(Kh + j0n * 64 + koff[L], kw + L * 1024);
#pragma unroll
            for (int L = 0; L < 4; ++L) gld_lds16(Vh + j0n + voff[L], vw + L * 1024);
        }

        int j0 = (t * 4 + w) * 32;

        // ---- hoisted QK: all 4 accumulators before any softmax ----
        f32x4 s[2][2];
        __builtin_amdgcn_s_setprio(1);
#pragma unroll
        for (int qt = 0; qt < 2; ++qt) {
            s[qt][0] = (f32x4){0.f, 0.f, 0.f, 0.f};
            s[qt][1] = (f32x4){0.f, 0.f, 0.f, 0.f};
            s[qt][0] = __builtin_amdgcn_mfma_f32_16x16x32_bf16(aq[qt][0], bk0a, s[qt][0], 0, 0, 0);
            s[qt][1] = __builtin_amdgcn_mfma_f32_16x16x32_bf16(aq[qt][0], bk1a, s[qt][1], 0, 0, 0);
            s[qt][0] = __builtin_amdgcn_mfma_f32_16x16x32_bf16(aq[qt][1], bk0b, s[qt][0], 0, 0, 0);
            s[qt][1] = __builtin_amdgcn_mfma_f32_16x16x32_bf16(aq[qt][1], bk1b, s[qt][1], 0, 0, 0);
        }
        __builtin_amdgcn_s_setprio(0);

#pragma unroll
        for (int qt = 0; qt < 2; ++qt) {
            int iqt0 = i0 + qt * 16;
            int iq = iqt0 + qd * 4;
            bool lowc  = (j0 + 31 - iqt0) <= -64;   // whole tile clamps to d=0
            bool highc = (j0 - (iqt0 + 15)) >= 64;  // whole tile clamps to d=128
            if (lowc || highc) {
                int d = lowc ? 0 : 128;
                float4 gg = lrg4[d];                // wave-uniform broadcast; use .x/.y
#pragma unroll
                for (int r = 0; r < 4; ++r) {
                    float t0 = EXP2(s[qt][0][r] + gg.x);
                    float t1 = EXP2(s[qt][1][r] + gg.x);
                    lp2[qt][r] += t0 + t1;
                    Ptu[w][qd * 4 + r][c] = pk2(t0 * gg.y, t1 * gg.y);
                }
            } else {
#pragma unroll
                for (int r = 0; r < 4; ++r) {
                    int i = iq + r;
                    int im1 = j0 + 2 * c - i;       // j - i for even column
                    int idx = (im1 < -64) ? 129 : ((im1 > 64 ? 64 : im1) + 64);
                    float4 g = lrg4[idx];           // (rel[d0],gate[d0],rel[d1],gate[d1])
                    float t0 = EXP2(s[qt][0][r] + g.x);
                    float t1 = EXP2(s[qt][1][r] + g.z);
                    lp2[qt][r] += t0 + t1;
                    Ptu[w][qd * 4 + r][c] = pk2(t0 * g.y, t1 * g.w);
                }
            }
            // same-wave RAW on Ptu: lgkmcnt ordering, no barrier needed
            bf16x8 ap = ld8((const unsigned short*)&Ptu[w][c][0] + qd * 8);
            __builtin_amdgcn_s_setprio(1);
#pragma unroll
            for (int db = 0; db < 4; ++db)
                o2[qt][db] = __builtin_amdgcn_mfma_f32_16x16x32_bf16(ap, bv[db], o2[qt][db], 0, 0, 0);
            __builtin_amdgcn_s_setprio(0);
        }
    }

    // ---- cross-wave combine (red overlaps staging slabs: barrier before reuse;
    //      last iter issued no prefetch, so no async LDS writes are in flight) ----
    __syncthreads();
    if (w > 0) {
        float* dst = red + (w - 1) * (64 * 41) + lane * 41;
#pragma unroll
        for (int qt = 0; qt < 2; ++qt)
#pragma unroll
            for (int db = 0; db < 4; ++db)
#pragma unroll
                for (int r = 0; r < 4; ++r)
                    dst[qt * 16 + db * 4 + r] = o2[qt][db][r];
#pragma unroll
        for (int qt = 0; qt < 2; ++qt)
#pragma unroll
            for (int r = 0; r < 4; ++r)
                dst[32 + qt * 4 + r] = lp2[qt][r];
    }
    __syncthreads();
    if (w == 0) {
#pragma unroll
        for (int ww = 0; ww < 3; ++ww) {
            const float* src = red + ww * (64 * 41) + lane * 41;
#pragma unroll
            for (int qt = 0; qt < 2; ++qt) {
#pragma unroll
                for (int db = 0; db < 4; ++db)
#pragma unroll
                    for (int r = 0; r < 4; ++r)
                        o2[qt][db][r] += src[qt * 16 + db * 4 + r];
#pragma unroll
                for (int r = 0; r < 4; ++r)
                    lp2[qt][r] += src[32 + qt * 4 + r];
            }
        }
#pragma unroll
        for (int qt = 0; qt < 2; ++qt)
#pragma unroll
            for (int r = 0; r < 4; ++r) {
                lp2[qt][r] += __shfl_xor(lp2[qt][r], 1);
                lp2[qt][r] += __shfl_xor(lp2[qt][r], 2);
                lp2[qt][r] += __shfl_xor(lp2[qt][r], 4);
                lp2[qt][r] += __shfl_xor(lp2[qt][r], 8);
            }
#pragma unroll
        for (int qt = 0; qt < 2; ++qt)
#pragma unroll
            for (int db = 0; db < 4; ++db)
#pragma unroll
                for (int r = 0; r < 4; ++r) {
                    int row = b * 2048 + i0 + qt * 16 + qd * 4 + r;
                    int col = h * 64 + db * 16 + c;
                    Ob[row * 512 + col] = f2bf(o2[qt][db][r] / lp2[qt][r]);
                }
    }
}

// ------------- Output GEMM v3 (R9-proven): dbuf staging, counted vmcnt, grid (64,8) --
__global__ __launch_bounds__(256, 4)
void ca_gemm_out(const unsigned short* __restrict__ A,
                 const unsigned short* __restrict__ BT,
                 const float* __restrict__ bias,
                 float* __restrict__ out) {
    __shared__ __align__(16) unsigned short Ash[2][64 * 64];
    __shared__ __align__(16) unsigned short Bsh[2][64 * 64];
    int w = threadIdx.x >> 6, lane = threadIdx.x & 63;
    int c = lane & 15, qd = lane >> 4;
    int m0 = blockIdx.x * 64 + w * 16;
    int n0 = blockIdx.y * 64;

    int lr = lane >> 3, ls = lane & 7;
    int soff = lr * 512 + ((ls ^ (lr & 7)) << 3);
    const unsigned short* Ab = A + (blockIdx.x * 64) * 512 + soff;
    const unsigned short* Bb = BT + n0 * 512 + soff;

#pragma unroll
    for (int L = 0; L < 2; ++L) {
        gld_lds16(Ab + (w * 16 + L * 8) * 512, (char*)Ash[0] + (w * 16 + L * 8) * 128);
        gld_lds16(Bb + (w * 16 + L * 8) * 512, (char*)Bsh[0] + (w * 16 + L * 8) * 128);
    }

    f32x4 acc[4];
#pragma unroll
    for (int nb = 0; nb < 4; ++nb) acc[nb] = (f32x4){0.f, 0.f, 0.f, 0.f};

    int cs = c & 7;
#pragma unroll
    for (int k = 0; k < 8; ++k) {
        int b = k & 1;
        if (k < 7) {
            int k0 = (k + 1) * 64;
#pragma unroll
            for (int L = 0; L < 2; ++L) {
                gld_lds16(Ab + k0 + (w * 16 + L * 8) * 512, (char*)Ash[b ^ 1] + (w * 16 + L * 8) * 128);
                gld_lds16(Bb + k0 + (w * 16 + L * 8) * 512, (char*)Bsh[b ^ 1] + (w * 16 + L * 8) * 128);
            }
            asm volatile("s_waitcnt vmcnt(4)" ::: "memory");
        } else {
            asm volatile("s_waitcnt vmcnt(0)" ::: "memory");
        }
        __syncthreads();
        bf16x8 a[2], bq[4][2];
#pragma unroll
        for (int kk = 0; kk < 2; ++kk)
            a[kk] = ld8((const unsigned short*)((char*)Ash[b] +
                        (w * 16 + c) * 128 + (((kk * 4 + qd) ^ cs) << 4)));
#pragma unroll
        for (int nb = 0; nb < 4; ++nb)
#pragma unroll
            for (int kk = 0; kk < 2; ++kk)
                bq[nb][kk] = ld8((const unsigned short*)((char*)Bsh[b] +
                                (nb * 16 + c) * 128 + (((kk * 4 + qd) ^ cs) << 4)));
        asm volatile("s_waitcnt lgkmcnt(0)" ::: "memory");
        __syncthreads();
#pragma unroll
        for (int kk = 0; kk < 2; ++kk)
#pragma unroll
            for (int nb = 0; nb < 4; ++nb)
                acc[nb] = __builtin_amdgcn_mfma_f32_16x16x32_bf16(a[kk], bq[nb][kk], acc[nb], 0, 0, 0);
    }
#pragma unroll
    for (int nb = 0; nb < 4; ++nb) {
#pragma unroll
        for (int r = 0; r < 4; ++r) {
            int row = m0 + qd * 4 + r;
            int col = n0 + nb * 16 + c;
            out[row * 512 + col] = acc[nb][r] + bias[col];
        }
    }
}

extern "C" void kernel_launch(void* const* d_in, const int* in_sizes, int n_in,
                              void* d_out, int out_size, void* d_ws, size_t ws_size,
                              hipStream_t stream) {
    const float* x   = (const float*)d_in[0];
    const float* Wq  = (const float*)d_in[1];
    const float* Wk  = (const float*)d_in[2];
    const float* Wv  = (const float*)d_in[3];
    const float* rel = (const float*)d_in[4];
    const float* cem = (const float*)d_in[5];
    const float* Wo  = (const float*)d_in[6];
    const float* bo  = (const float*)d_in[7];
    float* out = (float*)d_out;
    char* ws = (char*)d_ws;

    unsigned short* wts = (unsigned short*)(ws + 4194304);    // 1.5 MB (Wq,Wk,Wv ^T)
    unsigned short* woT = (unsigned short*)(ws + 5767168);    // 512 KB Wo^T
    unsigned short* qkv = (unsigned short*)(ws + 6291456);    // q,k
    unsigned short* vt  = (unsigned short*)(ws + 18874368);   // 4 MB  vT bf16 [bh][DH][N]
    unsigned short* ob  = (unsigned short*)(ws + 23068672);   // 4 MB

    hipLaunchKernelGGL(ca_prep, dim3(192), dim3(256), 0, stream, Wq, Wk, Wv, wts);
    hipLaunchKernelGGL(ca_gemm_proj, dim3(32, 24), dim3(256), 0, stream, x, wts, qkv, vt);
    hipLaunchKernelGGL(ca_flash, dim3(1088), dim3(256), 0, stream,
                       qkv, qkv + 2097152, vt, rel, cem, ob, Wo, woT);
    hipLaunchKernelGGL(ca_gemm_out, dim3(64, 8), dim3(256), 0, stream, ob, woT, bo, out);
}

// Round 14
// 137.043 us; speedup vs baseline: 1.1264x; 1.1264x over previous
//
#include <hip/hip_runtime.h>
#include <hip/hip_bf16.h>
#include <stdint.h>

// Problem constants
#define BB 2
#define NN 2048
#define DD 512
#define HH 8
#define DHH 64
// bh count = 16, per-head Q/K/V = 2048*64 elems = 131072

typedef __attribute__((ext_vector_type(8))) short bf16x8;   // 8 bf16 = 4 VGPR
typedef __attribute__((ext_vector_type(4))) float f32x4;    // MFMA C/D frag

#define LOG2E 1.44269504088896340736f

#if __has_builtin(__builtin_amdgcn_exp2f)
#define QSCALE (0.125f * LOG2E)
#define EXP2(x) __builtin_amdgcn_exp2f(x)
#else
#define QSCALE 0.125f
#define EXP2(x) __expf(x)
#endif

static __device__ __forceinline__ unsigned short f2bf(float f) {
    union { float f; unsigned u; } v; v.f = f;
    unsigned r = v.u + 0x7fffu + ((v.u >> 16) & 1u);  // RNE
    return (unsigned short)(r >> 16);
}

// pack two floats -> bf16 pair, COMPILER-VISIBLE (emits v_cvt_pk_bf16_f32)
static __device__ __forceinline__ unsigned pk2(float a, float b) {
    __hip_bfloat162 h = __float22bfloat162_rn(make_float2(a, b));
    union { __hip_bfloat162 h; unsigned u; } cv; cv.h = h;
    return cv.u;
}

static __device__ __forceinline__ bf16x8 ld8(const unsigned short* p) {
    bf16x8 v; __builtin_memcpy(&v, p, 16); return v;
}

// async global->LDS, 16B per lane; LDS dest = wave-uniform base + lane*16
static __device__ __forceinline__ void gld_lds16(const void* g, void* l) {
    __builtin_amdgcn_global_load_lds((const __attribute__((address_space(1))) void*)g,
                                     (__attribute__((address_space(3))) void*)l, 16, 0, 0);
}

// ---------------- prep (R12-proven): cast x -> bf16 (2 float4/thread), transpose Wq/Wk/Wv
// grid 1216: bx<1024 x-cast; bx>=1024: 192 weight-transpose blocks.
// (Wo transpose rides on ca_flash blocks 0..63.)
__global__ void ca_prep(const float* __restrict__ x,
                        const float* __restrict__ w0, const float* __restrict__ w1,
                        const float* __restrict__ w2,
                        unsigned short* __restrict__ xb, unsigned short* __restrict__ wts) {
    __shared__ float T[64][65];
    int bx = blockIdx.x;
    if (bx < 1024) {
        int gid = bx * 512 + threadIdx.x;
#pragma unroll
        for (int j = 0; j < 2; ++j) {
            float4 v = ((const float4*)x)[gid + j * 256];
            ushort4 o;
            o.x = f2bf(v.x); o.y = f2bf(v.y); o.z = f2bf(v.z); o.w = f2bf(v.w);
            ((ushort4*)xb)[gid + j * 256] = o;
        }
        return;
    }
    int bb = bx - 1024;
    int z = bb >> 6, t = bb & 63;
    const float* W = (z == 0) ? w0 : (z == 1) ? w1 : w2;
    unsigned short* out = wts + z * 262144;
    int k0 = (t & 7) << 6, n0 = (t >> 3) << 6;
    int c = threadIdx.x & 63, r4 = threadIdx.x >> 6;
#pragma unroll
    for (int rr = 0; rr < 16; ++rr) {
        int r = r4 * 16 + rr;
        T[r][c] = W[(k0 + r) * 512 + n0 + c];
    }
    __syncthreads();
#pragma unroll
    for (int rr = 0; rr < 16; ++rr) {
        int r = r4 * 16 + rr;
        out[(n0 + r) * 512 + k0 + c] = f2bf(T[c][r]);
    }
}

// ------------- QKV projection GEMM v3 (R12-proven): dbuf staging, counted vmcnt ------
__global__ __launch_bounds__(256, 3)
void ca_gemm_proj(const unsigned short* __restrict__ A,
                  const unsigned short* __restrict__ wts,
                  unsigned short* __restrict__ qkv,
                  unsigned short* __restrict__ vt) {
    __shared__ __align__(16) unsigned short Ash[2][128 * 64];
    __shared__ __align__(16) unsigned short Bsh[2][64 * 64];
    int z = blockIdx.y >> 3;
    const unsigned short* BT = wts + z * 262144;
    unsigned short* out = qkv + z * 2097152;
    int w = threadIdx.x >> 6, lane = threadIdx.x & 63;
    int c = lane & 15, qd = lane >> 4;
    int m0 = blockIdx.x * 128 + w * 16;          // wave covers m0 and m0+64
    int n0 = (blockIdx.y & 7) * 64;

    int lr = lane >> 3, ls = lane & 7;
    int soff = lr * 512 + ((ls ^ (lr & 7)) << 3);
    const unsigned short* Ab = A + (blockIdx.x * 128) * 512 + soff;
    const unsigned short* Bb = BT + n0 * 512 + soff;

    // prologue: stage chunk 0 -> buf 0
#pragma unroll
    for (int L = 0; L < 4; ++L)
        gld_lds16(Ab + (w * 32 + L * 8) * 512, (char*)Ash[0] + (w * 32 + L * 8) * 128);
#pragma unroll
    for (int L = 0; L < 2; ++L)
        gld_lds16(Bb + (w * 16 + L * 8) * 512, (char*)Bsh[0] + (w * 16 + L * 8) * 128);

    f32x4 acc[2][4];
#pragma unroll
    for (int mt = 0; mt < 2; ++mt)
#pragma unroll
        for (int nb = 0; nb < 4; ++nb) acc[mt][nb] = (f32x4){0.f, 0.f, 0.f, 0.f};

    int cs = c & 7;
#pragma unroll
    for (int k = 0; k < 8; ++k) {
        int b = k & 1;
        if (k < 7) {
            int k0 = (k + 1) * 64;
#pragma unroll
            for (int L = 0; L < 4; ++L)
                gld_lds16(Ab + k0 + (w * 32 + L * 8) * 512, (char*)Ash[b ^ 1] + (w * 32 + L * 8) * 128);
#pragma unroll
            for (int L = 0; L < 2; ++L)
                gld_lds16(Bb + k0 + (w * 16 + L * 8) * 512, (char*)Bsh[b ^ 1] + (w * 16 + L * 8) * 128);
            asm volatile("s_waitcnt vmcnt(6)" ::: "memory");   // chunk k done, k+1 in flight
        } else {
            asm volatile("s_waitcnt vmcnt(0)" ::: "memory");
        }
        __syncthreads();
        bf16x8 a[2][2], bq[4][2];
#pragma unroll
        for (int mt = 0; mt < 2; ++mt)
#pragma unroll
            for (int kk = 0; kk < 2; ++kk)
                a[mt][kk] = ld8((const unsigned short*)((char*)Ash[b] +
                                (w * 16 + mt * 64 + c) * 128 + (((kk * 4 + qd) ^ cs) << 4)));
#pragma unroll
        for (int nb = 0; nb < 4; ++nb)
#pragma unroll
            for (int kk = 0; kk < 2; ++kk)
                bq[nb][kk] = ld8((const unsigned short*)((char*)Bsh[b] +
                                (nb * 16 + c) * 128 + (((kk * 4 + qd) ^ cs) << 4)));
        asm volatile("s_waitcnt lgkmcnt(0)" ::: "memory");
        __syncthreads();
#pragma unroll
        for (int kk = 0; kk < 2; ++kk)
#pragma unroll
            for (int nb = 0; nb < 4; ++nb) {
                acc[0][nb] = __builtin_amdgcn_mfma_f32_16x16x32_bf16(a[0][kk], bq[nb][kk], acc[0][nb], 0, 0, 0);
                acc[1][nb] = __builtin_amdgcn_mfma_f32_16x16x32_bf16(a[1][kk], bq[nb][kk], acc[1][nb], 0, 0, 0);
            }
    }

    if (z == 2) {
        // V: write transposed [bh][d][i], 4 consecutive i packed per store
#pragma unroll
        for (int mt = 0; mt < 2; ++mt) {
            int ib = m0 + mt * 64 + qd * 4;      // i base (4-aligned)
            int b = ib >> 11, i = ib & 2047;
#pragma unroll
            for (int nb = 0; nb < 4; ++nb) {
                int col = n0 + nb * 16 + c;      // h*64 + d
                int h = col >> 6, d = col & 63;
                ushort4 pk;
                pk.x = f2bf(acc[mt][nb][0]); pk.y = f2bf(acc[mt][nb][1]);
                pk.z = f2bf(acc[mt][nb][2]); pk.w = f2bf(acc[mt][nb][3]);
                *(ushort4*)(vt + (((b << 3) + h) * 64 + d) * 2048 + i) = pk;
            }
        }
    } else {
        float scale = (z == 0) ? QSCALE : 1.0f;
#pragma unroll
        for (int mt = 0; mt < 2; ++mt)
#pragma unroll
            for (int nb = 0; nb < 4; ++nb) {
#pragma unroll
                for (int r = 0; r < 4; ++r) {
                    int row = m0 + mt * 64 + qd * 4 + r;
                    int col = n0 + nb * 16 + c;
                    int b = row >> 11, i = row & 2047, h = col >> 6, d = col & 63;
                    out[(((b << 3) + h) * 2048 + i) * 64 + d] = f2bf(acc[mt][nb][r] * scale);
                }
            }
    }
}

// ------------- Flash attention v11 (R13-proven): pair-table + R9 body + Wo rider ----
// lrg4[130] float4: entry d = (rel[d],gate[d],rel[min(d+1,128)],gate[min(d+1,128)]);
// entry 129 = both-low-clamped. idx = im1 < -64 ? 129 : min(im1,64)+64.
__global__ __launch_bounds__(256, 4)
void ca_flash(const unsigned short* __restrict__ Q,
              const unsigned short* __restrict__ K,
              const unsigned short* __restrict__ VT,
              const float* __restrict__ rel_pos,
              const float* __restrict__ c_emb,
              unsigned short* __restrict__ Ob,
              const float* __restrict__ Wo,
              unsigned short* __restrict__ woT) {
    __shared__ __align__(16) char smem[38944];

    if (blockIdx.x < 64) {
        // ---- Wo transpose-cast rider ----
        float (*T)[65] = (float (*)[65])smem;     // 16.6KB < 38.9KB
        int t = blockIdx.x;
        int k0 = (t & 7) << 6, n0 = (t >> 3) << 6;
        int c = threadIdx.x & 63, r4 = threadIdx.x >> 6;
#pragma unroll
        for (int rr = 0; rr < 16; ++rr) {
            int r = r4 * 16 + rr;
            T[r][c] = Wo[(k0 + r) * 512 + n0 + c];
        }
        __syncthreads();
#pragma unroll
        for (int rr = 0; rr < 16; ++rr) {
            int r = r4 * 16 + rr;
            woT[(n0 + r) * 512 + k0 + c] = f2bf(T[c][r]);
        }
        return;
    }

    unsigned (*Ptu)[16][16] = (unsigned (*)[16][16])(smem + 32768);
    float* red = (float*)smem;                       // [3][64][41] floats
    float4* lrg4 = (float4*)(smem + 36864);          // 130 pair-entries

    int bx = blockIdx.x - 64;
    int xcd = bx & 7, slot = bx >> 3;           // slot 0..127
    int bh = xcd + ((slot >> 6) << 3);          // heads {xcd, xcd+8} per XCD
    int it = slot & 63;
    int b = bh >> 3, h = bh & 7;
    int w = threadIdx.x >> 6, lane = threadIdx.x & 63;
    int c = lane & 15, qd = lane >> 4;
    int i0 = it * 32;

    if (threadIdx.x < 130) {
        int e1 = (threadIdx.x < 129) ? threadIdx.x : 0;
        int e2 = (threadIdx.x < 129) ? ((threadIdx.x < 128) ? threadIdx.x + 1 : 128) : 0;
        float4 v;
        v.x = rel_pos[e1 * 8 + h] * QSCALE; v.y = c_emb[e1 * 8 + h];
        v.z = rel_pos[e2 * 8 + h] * QSCALE; v.w = c_emb[e2 * 8 + h];
        lrg4[threadIdx.x] = v;
    }

    const unsigned short* Qh = Q  + bh * 131072;
    const unsigned short* Kh = K  + bh * 131072;
    const unsigned short* Vh = VT + bh * 131072;
    char* kw = smem + w * 4096;                 // wave-private K slab (32 rows x 128B)
    char* vw = smem + 16384 + w * 4096;         // wave-private V slab (64 rows x 64B)

    int koff[4], voff[4];
#pragma unroll
    for (int L = 0; L < 4; ++L) {
        int kr = L * 8 + (lane >> 3);
        koff[L] = kr * 64 + (((lane & 7) ^ ((kr >> 1) & 7)) << 3);
        int vr = L * 16 + (lane >> 2);
        voff[L] = vr * 2048 + (((lane & 3) ^ ((lane >> 3) & 3)) << 3);
    }

    // prologue: stage tile t=0 (j0 = w*32): K first, then V (vmcnt(4) split)
    {
        int j0 = w * 32;
#pragma unroll
        for (int L = 0; L < 4; ++L) gld_lds16(Kh + j0 * 64 + koff[L], kw + L * 1024);
#pragma unroll
        for (int L = 0; L < 4; ++L) gld_lds16(Vh + j0 + voff[L], vw + L * 1024);
    }

    bf16x8 aq[2][2];
#pragma unroll
    for (int qt = 0; qt < 2; ++qt) {
        aq[qt][0] = ld8(Qh + (i0 + qt * 16 + c) * 64 + qd * 8);
        aq[qt][1] = ld8(Qh + (i0 + qt * 16 + c) * 64 + 32 + qd * 8);
    }

    f32x4 o2[2][4];
    float lp2[2][4];
#pragma unroll
    for (int qt = 0; qt < 2; ++qt)
#pragma unroll
        for (int db = 0; db < 4; ++db) {
            o2[qt][db] = (f32x4){0.f, 0.f, 0.f, 0.f};
            lp2[qt][db] = 0.f;
        }

    __syncthreads();   // lrg4 ready (also drains prologue stage - harmless)

    int ksw  = c & 7;          // (row>>1)&7 for K rows 2c, 2c+1
    int vsw  = (c >> 1) & 3;   // (row>>1)&3 for V rows db*16+c

    for (int t = 0; t < 16; ++t) {
        asm volatile("s_waitcnt vmcnt(4)" ::: "memory");
        __builtin_amdgcn_sched_barrier(0);
        bf16x8 bk0a = ld8((const unsigned short*)(kw + (2 * c) * 128     + (((qd)     ^ ksw) << 4)));
        bf16x8 bk0b = ld8((const unsigned short*)(kw + (2 * c) * 128     + (((qd + 4) ^ ksw) << 4)));
        bf16x8 bk1a = ld8((const unsigned short*)(kw + (2 * c + 1) * 128 + (((qd)     ^ ksw) << 4)));
        bf16x8 bk1b = ld8((const unsigned short*)(kw + (2 * c + 1) * 128 + (((qd + 4) ^ ksw) << 4)));
        asm volatile("s_waitcnt vmcnt(0)" ::: "memory");
        __builtin_amdgcn_sched_barrier(0);
        bf16x8 bv[4];
#pragma unroll
        for (int db = 0; db < 4; ++db)
            bv[db] = ld8((const unsigned short*)(vw + (db * 16 + c) * 64 + ((qd ^ vsw) << 4)));
        asm volatile("s_waitcnt lgkmcnt(0)" ::: "memory");
        __builtin_amdgcn_sched_barrier(0);
        if (t < 15) {
            int j0n = ((t + 1) * 4 + w) * 32;
#pragma unroll
            for (int L = 0; L < 4; ++L) gld_lds16(Kh + j0n * 64 + koff[L], kw + L * 1024);
#pragma unroll
            for (int L = 0; L < 4; ++L) gld_lds16(Vh + j0n + voff[L], vw + L * 1024);
        }

        int j0 = (t * 4 + w) * 32;

        // ---- hoisted QK: all 4 accumulators before any softmax ----
        f32x4 s[2][2];
        __builtin_amdgcn_s_setprio(1);
#pragma unroll
        for (int qt = 0; qt < 2; ++qt) {
            s[qt][0] = (f32x4){0.f, 0.f, 0.f, 0.f};
            s[qt][1] = (f32x4){0.f, 0.f, 0.f, 0.f};
            s[qt][0] = __builtin_amdgcn_mfma_f32_16x16x32_bf16(aq[qt][0], bk0a, s[qt][0], 0, 0, 0);
            s[qt][1] = __builtin_amdgcn_mfma_f32_16x16x32_bf16(aq[qt][0], bk1a, s[qt][1], 0, 0, 0);
            s[qt][0] = __builtin_amdgcn_mfma_f32_16x16x32_bf16(aq[qt][1], bk0b, s[qt][0], 0, 0, 0);
            s[qt][1] = __builtin_amdgcn_mfma_f32_16x16x32_bf16(aq[qt][1], bk1b, s[qt][1], 0, 0, 0);
        }
        __builtin_amdgcn_s_setprio(0);

#pragma unroll
        for (int qt = 0; qt < 2; ++qt) {
            int iqt0 = i0 + qt * 16;
            int iq = iqt0 + qd * 4;
            bool lowc  = (j0 + 31 - iqt0) <= -64;   // whole tile clamps to d=0
            bool highc = (j0 - (iqt0 + 15)) >= 64;  // whole tile clamps to d=128
            if (lowc || highc) {
                int d = lowc ? 0 : 128;
                float4 gg = lrg4[d];                // wave-uniform broadcast; use .x/.y
#pragma unroll
                for (int r = 0; r < 4; ++r) {
                    float t0 = EXP2(s[qt][0][r] + gg.x);
                    float t1 = EXP2(s[qt][1][r] + gg.x);
                    lp2[qt][r] += t0 + t1;
                    Ptu[w][qd * 4 + r][c] = pk2(t0 * gg.y, t1 * gg.y);
                }
            } else {
#pragma unroll
                for (int r = 0; r < 4; ++r) {
                    int i = iq + r;
                    int im1 = j0 + 2 * c - i;       // j - i for even column
                    int idx = (im1 < -64) ? 129 : ((im1 > 64 ? 64 : im1) + 64);
                    float4 g = lrg4[idx];           // (rel[d0],gate[d0],rel[d1],gate[d1])
                    float t0 = EXP2(s[qt][0][r] + g.x);
                    float t1 = EXP2(s[qt][1][r] + g.z);
                    lp2[qt][r] += t0 + t1;
                    Ptu[w][qd * 4 + r][c] = pk2(t0 * g.y, t1 * g.w);
                }
            }
            // same-wave RAW on Ptu: lgkmcnt ordering, no barrier needed
            bf16x8 ap = ld8((const unsigned short*)&Ptu[w][c][0] + qd * 8);
            __builtin_amdgcn_s_setprio(1);
#pragma unroll
            for (int db = 0; db < 4; ++db)
                o2[qt][db] = __builtin_amdgcn_mfma_f32_16x16x32_bf16(ap, bv[db], o2[qt][db], 0, 0, 0);
            __builtin_amdgcn_s_setprio(0);
        }
    }

    // ---- cross-wave combine (red overlaps staging slabs: barrier before reuse;
    //      last iter issued no prefetch, so no async LDS writes are in flight) ----
    __syncthreads();
    if (w > 0) {
        float* dst = red + (w - 1) * (64 * 41) + lane * 41;
#pragma unroll
        for (int qt = 0; qt < 2; ++qt)
#pragma unroll
            for (int db = 0; db < 4; ++db)
#pragma unroll
                for (int r = 0; r < 4; ++r)
                    dst[qt * 16 + db * 4 + r] = o2[qt][db][r];
#pragma unroll
        for (int qt = 0; qt < 2; ++qt)
#pragma unroll
            for (int r = 0; r < 4; ++r)
                dst[32 + qt * 4 + r] = lp2[qt][r];
    }
    __syncthreads();
    if (w == 0) {
#pragma unroll
        for (int ww = 0; ww < 3; ++ww) {
            const float* src = red + ww * (64 * 41) + lane * 41;
#pragma unroll
            for (int qt = 0; qt < 2; ++qt) {
#pragma unroll
                for (int db = 0; db < 4; ++db)
#pragma unroll
                    for (int r = 0; r < 4; ++r)
                        o2[qt][db][r] += src[qt * 16 + db * 4 + r];
#pragma unroll
                for (int r = 0; r < 4; ++r)
                    lp2[qt][r] += src[32 + qt * 4 + r];
            }
        }
#pragma unroll
        for (int qt = 0; qt < 2; ++qt)
#pragma unroll
            for (int r = 0; r < 4; ++r) {
                lp2[qt][r] += __shfl_xor(lp2[qt][r], 1);
                lp2[qt][r] += __shfl_xor(lp2[qt][r], 2);
                lp2[qt][r] += __shfl_xor(lp2[qt][r], 4);
                lp2[qt][r] += __shfl_xor(lp2[qt][r], 8);
            }
#pragma unroll
        for (int qt = 0; qt < 2; ++qt)
#pragma unroll
            for (int db = 0; db < 4; ++db)
#pragma unroll
                for (int r = 0; r < 4; ++r) {
                    int row = b * 2048 + i0 + qt * 16 + qd * 4 + r;
                    int col = h * 64 + db * 16 + c;
                    Ob[row * 512 + col] = f2bf(o2[qt][db][r] / lp2[qt][r]);
                }
    }
}

// ------------- Output GEMM v3 (R9-proven): dbuf staging, counted vmcnt, grid (64,8) --
__global__ __launch_bounds__(256, 4)
void ca_gemm_out(const unsigned short* __restrict__ A,
                 const unsigned short* __restrict__ BT,
                 const float* __restrict__ bias,
                 float* __restrict__ out) {
    __shared__ __align__(16) unsigned short Ash[2][64 * 64];
    __shared__ __align__(16) unsigned short Bsh[2][64 * 64];
    int w = threadIdx.x >> 6, lane = threadIdx.x & 63;
    int c = lane & 15, qd = lane >> 4;
    int m0 = blockIdx.x * 64 + w * 16;
    int n0 = blockIdx.y * 64;

    int lr = lane >> 3, ls = lane & 7;
    int soff = lr * 512 + ((ls ^ (lr & 7)) << 3);
    const unsigned short* Ab = A + (blockIdx.x * 64) * 512 + soff;
    const unsigned short* Bb = BT + n0 * 512 + soff;

#pragma unroll
    for (int L = 0; L < 2; ++L) {
        gld_lds16(Ab + (w * 16 + L * 8) * 512, (char*)Ash[0] + (w * 16 + L * 8) * 128);
        gld_lds16(Bb + (w * 16 + L * 8) * 512, (char*)Bsh[0] + (w * 16 + L * 8) * 128);
    }

    f32x4 acc[4];
#pragma unroll
    for (int nb = 0; nb < 4; ++nb) acc[nb] = (f32x4){0.f, 0.f, 0.f, 0.f};

    int cs = c & 7;
#pragma unroll
    for (int k = 0; k < 8; ++k) {
        int b = k & 1;
        if (k < 7) {
            int k0 = (k + 1) * 64;
#pragma unroll
            for (int L = 0; L < 2; ++L) {
                gld_lds16(Ab + k0 + (w * 16 + L * 8) * 512, (char*)Ash[b ^ 1] + (w * 16 + L * 8) * 128);
                gld_lds16(Bb + k0 + (w * 16 + L * 8) * 512, (char*)Bsh[b ^ 1] + (w * 16 + L * 8) * 128);
            }
            asm volatile("s_waitcnt vmcnt(4)" ::: "memory");
        } else {
            asm volatile("s_waitcnt vmcnt(0)" ::: "memory");
        }
        __syncthreads();
        bf16x8 a[2], bq[4][2];
#pragma unroll
        for (int kk = 0; kk < 2; ++kk)
            a[kk] = ld8((const unsigned short*)((char*)Ash[b] +
                        (w * 16 + c) * 128 + (((kk * 4 + qd) ^ cs) << 4)));
#pragma unroll
        for (int nb = 0; nb < 4; ++nb)
#pragma unroll
            for (int kk = 0; kk < 2; ++kk)
                bq[nb][kk] = ld8((const unsigned short*)((char*)Bsh[b] +
                                (nb * 16 + c) * 128 + (((kk * 4 + qd) ^ cs) << 4)));
        asm volatile("s_waitcnt lgkmcnt(0)" ::: "memory");
        __syncthreads();
#pragma unroll
        for (int kk = 0; kk < 2; ++kk)
#pragma unroll
            for (int nb = 0; nb < 4; ++nb)
                acc[nb] = __builtin_amdgcn_mfma_f32_16x16x32_bf16(a[kk], bq[nb][kk], acc[nb], 0, 0, 0);
    }
#pragma unroll
    for (int nb = 0; nb < 4; ++nb) {
#pragma unroll
        for (int r = 0; r < 4; ++r) {
            int row = m0 + qd * 4 + r;
            int col = n0 + nb * 16 + c;
            out[row * 512 + col] = acc[nb][r] + bias[col];
        }
    }
}

extern "C" void kernel_launch(void* const* d_in, const int* in_sizes, int n_in,
                              void* d_out, int out_size, void* d_ws, size_t ws_size,
                              hipStream_t stream) {
    const float* x   = (const float*)d_in[0];
    const float* Wq  = (const float*)d_in[1];
    const float* Wk  = (const float*)d_in[2];
    const float* Wv  = (const float*)d_in[3];
    const float* rel = (const float*)d_in[4];
    const float* cem = (const float*)d_in[5];
    const float* Wo  = (const float*)d_in[6];
    const float* bo  = (const float*)d_in[7];
    float* out = (float*)d_out;
    char* ws = (char*)d_ws;

    unsigned short* xb  = (unsigned short*)(ws);              // 4 MB
    unsigned short* wts = (unsigned short*)(ws + 4194304);    // 1.5 MB (Wq,Wk,Wv ^T)
    unsigned short* woT = (unsigned short*)(ws + 5767168);    // 512 KB Wo^T
    unsigned short* qkv = (unsigned short*)(ws + 6291456);    // q,k
    unsigned short* vt  = (unsigned short*)(ws + 18874368);   // 4 MB  vT bf16 [bh][DH][N]
    unsigned short* ob  = (unsigned short*)(ws + 23068672);   // 4 MB

    hipLaunchKernelGGL(ca_prep, dim3(1216), dim3(256), 0, stream, x, Wq, Wk, Wv, xb, wts);
    hipLaunchKernelGGL(ca_gemm_proj, dim3(32, 24), dim3(256), 0, stream, xb, wts, qkv, vt);
    hipLaunchKernelGGL(ca_flash, dim3(1088), dim3(256), 0, stream,
                       qkv, qkv + 2097152, vt, rel, cem, ob, Wo, woT);
    hipLaunchKernelGGL(ca_gemm_out, dim3(64, 8), dim3(256), 0, stream, ob, woT, bo, out);
}

// Round 15
// 136.769 us; speedup vs baseline: 1.1287x; 1.0020x over previous
//
#include <hip/hip_runtime.h>
#include <hip/hip_bf16.h>
#include <stdint.h>

// Problem constants
#define BB 2
#define NN 2048
#define DD 512
#define HH 8
#define DHH 64
// bh count = 16, per-head Q/K/V = 2048*64 elems = 131072

typedef __attribute__((ext_vector_type(8))) short bf16x8;   // 8 bf16 = 4 VGPR
typedef __attribute__((ext_vector_type(4))) float f32x4;    // MFMA C/D frag

#define LOG2E 1.44269504088896340736f

#if __has_builtin(__builtin_amdgcn_exp2f)
#define QSCALE (0.125f * LOG2E)
#define EXP2(x) __builtin_amdgcn_exp2f(x)
#else
#define QSCALE 0.125f
#define EXP2(x) __expf(x)
#endif

static __device__ __forceinline__ unsigned short f2bf(float f) {
    union { float f; unsigned u; } v; v.f = f;
    unsigned r = v.u + 0x7fffu + ((v.u >> 16) & 1u);  // RNE
    return (unsigned short)(r >> 16);
}

// pack two floats -> bf16 pair, COMPILER-VISIBLE (emits v_cvt_pk_bf16_f32)
static __device__ __forceinline__ unsigned pk2(float a, float b) {
    __hip_bfloat162 h = __float22bfloat162_rn(make_float2(a, b));
    union { __hip_bfloat162 h; unsigned u; } cv; cv.h = h;
    return cv.u;
}

static __device__ __forceinline__ bf16x8 ld8(const unsigned short* p) {
    bf16x8 v; __builtin_memcpy(&v, p, 16); return v;
}

// async global->LDS, 16B per lane; LDS dest = wave-uniform base + lane*16
static __device__ __forceinline__ void gld_lds16(const void* g, void* l) {
    __builtin_amdgcn_global_load_lds((const __attribute__((address_space(1))) void*)g,
                                     (__attribute__((address_space(3))) void*)l, 16, 0, 0);
}

// ---------------- prep (R12-proven): cast x -> bf16 (2 float4/thread), transpose Wq/Wk/Wv
// grid 1216: bx<1024 x-cast; bx>=1024: 192 weight-transpose blocks.
// (Wo transpose rides on ca_flash blocks 0..63.)
__global__ void ca_prep(const float* __restrict__ x,
                        const float* __restrict__ w0, const float* __restrict__ w1,
                        const float* __restrict__ w2,
                        unsigned short* __restrict__ xb, unsigned short* __restrict__ wts) {
    __shared__ float T[64][65];
    int bx = blockIdx.x;
    if (bx < 1024) {
        int gid = bx * 512 + threadIdx.x;
#pragma unroll
        for (int j = 0; j < 2; ++j) {
            float4 v = ((const float4*)x)[gid + j * 256];
            ushort4 o;
            o.x = f2bf(v.x); o.y = f2bf(v.y); o.z = f2bf(v.z); o.w = f2bf(v.w);
            ((ushort4*)xb)[gid + j * 256] = o;
        }
        return;
    }
    int bb = bx - 1024;
    int z = bb >> 6, t = bb & 63;
    const float* W = (z == 0) ? w0 : (z == 1) ? w1 : w2;
    unsigned short* out = wts + z * 262144;
    int k0 = (t & 7) << 6, n0 = (t >> 3) << 6;
    int c = threadIdx.x & 63, r4 = threadIdx.x >> 6;
#pragma unroll
    for (int rr = 0; rr < 16; ++rr) {
        int r = r4 * 16 + rr;
        T[r][c] = W[(k0 + r) * 512 + n0 + c];
    }
    __syncthreads();
#pragma unroll
    for (int rr = 0; rr < 16; ++rr) {
        int r = r4 * 16 + rr;
        out[(n0 + r) * 512 + k0 + c] = f2bf(T[c][r]);
    }
}

// ------------- QKV projection GEMM v3 (R12-proven): dbuf staging, counted vmcnt ------
__global__ __launch_bounds__(256, 3)
void ca_gemm_proj(const unsigned short* __restrict__ A,
                  const unsigned short* __restrict__ wts,
                  unsigned short* __restrict__ qkv,
                  unsigned short* __restrict__ vt) {
    __shared__ __align__(16) unsigned short Ash[2][128 * 64];
    __shared__ __align__(16) unsigned short Bsh[2][64 * 64];
    int z = blockIdx.y >> 3;
    const unsigned short* BT = wts + z * 262144;
    unsigned short* out = qkv + z * 2097152;
    int w = threadIdx.x >> 6, lane = threadIdx.x & 63;
    int c = lane & 15, qd = lane >> 4;
    int m0 = blockIdx.x * 128 + w * 16;          // wave covers m0 and m0+64
    int n0 = (blockIdx.y & 7) * 64;

    int lr = lane >> 3, ls = lane & 7;
    int soff = lr * 512 + ((ls ^ (lr & 7)) << 3);
    const unsigned short* Ab = A + (blockIdx.x * 128) * 512 + soff;
    const unsigned short* Bb = BT + n0 * 512 + soff;

    // prologue: stage chunk 0 -> buf 0
#pragma unroll
    for (int L = 0; L < 4; ++L)
        gld_lds16(Ab + (w * 32 + L * 8) * 512, (char*)Ash[0] + (w * 32 + L * 8) * 128);
#pragma unroll
    for (int L = 0; L < 2; ++L)
        gld_lds16(Bb + (w * 16 + L * 8) * 512, (char*)Bsh[0] + (w * 16 + L * 8) * 128);

    f32x4 acc[2][4];
#pragma unroll
    for (int mt = 0; mt < 2; ++mt)
#pragma unroll
        for (int nb = 0; nb < 4; ++nb) acc[mt][nb] = (f32x4){0.f, 0.f, 0.f, 0.f};

    int cs = c & 7;
#pragma unroll
    for (int k = 0; k < 8; ++k) {
        int b = k & 1;
        if (k < 7) {
            int k0 = (k + 1) * 64;
#pragma unroll
            for (int L = 0; L < 4; ++L)
                gld_lds16(Ab + k0 + (w * 32 + L * 8) * 512, (char*)Ash[b ^ 1] + (w * 32 + L * 8) * 128);
#pragma unroll
            for (int L = 0; L < 2; ++L)
                gld_lds16(Bb + k0 + (w * 16 + L * 8) * 512, (char*)Bsh[b ^ 1] + (w * 16 + L * 8) * 128);
            asm volatile("s_waitcnt vmcnt(6)" ::: "memory");   // chunk k done, k+1 in flight
        } else {
            asm volatile("s_waitcnt vmcnt(0)" ::: "memory");
        }
        __syncthreads();
        bf16x8 a[2][2], bq[4][2];
#pragma unroll
        for (int mt = 0; mt < 2; ++mt)
#pragma unroll
            for (int kk = 0; kk < 2; ++kk)
                a[mt][kk] = ld8((const unsigned short*)((char*)Ash[b] +
                                (w * 16 + mt * 64 + c) * 128 + (((kk * 4 + qd) ^ cs) << 4)));
#pragma unroll
        for (int nb = 0; nb < 4; ++nb)
#pragma unroll
            for (int kk = 0; kk < 2; ++kk)
                bq[nb][kk] = ld8((const unsigned short*)((char*)Bsh[b] +
                                (nb * 16 + c) * 128 + (((kk * 4 + qd) ^ cs) << 4)));
        asm volatile("s_waitcnt lgkmcnt(0)" ::: "memory");
        __syncthreads();
#pragma unroll
        for (int kk = 0; kk < 2; ++kk)
#pragma unroll
            for (int nb = 0; nb < 4; ++nb) {
                acc[0][nb] = __builtin_amdgcn_mfma_f32_16x16x32_bf16(a[0][kk], bq[nb][kk], acc[0][nb], 0, 0, 0);
                acc[1][nb] = __builtin_amdgcn_mfma_f32_16x16x32_bf16(a[1][kk], bq[nb][kk], acc[1][nb], 0, 0, 0);
            }
    }

    if (z == 2) {
        // V: write transposed [bh][d][i], 4 consecutive i packed per store
#pragma unroll
        for (int mt = 0; mt < 2; ++mt) {
            int ib = m0 + mt * 64 + qd * 4;      // i base (4-aligned)
            int b = ib >> 11, i = ib & 2047;
#pragma unroll
            for (int nb = 0; nb < 4; ++nb) {
                int col = n0 + nb * 16 + c;      // h*64 + d
                int h = col >> 6, d = col & 63;
                ushort4 pk;
                pk.x = f2bf(acc[mt][nb][0]); pk.y = f2bf(acc[mt][nb][1]);
                pk.z = f2bf(acc[mt][nb][2]); pk.w = f2bf(acc[mt][nb][3]);
                *(ushort4*)(vt + (((b << 3) + h) * 64 + d) * 2048 + i) = pk;
            }
        }
    } else {
        float scale = (z == 0) ? QSCALE : 1.0f;
#pragma unroll
        for (int mt = 0; mt < 2; ++mt)
#pragma unroll
            for (int nb = 0; nb < 4; ++nb) {
#pragma unroll
                for (int r = 0; r < 4; ++r) {
                    int row = m0 + mt * 64 + qd * 4 + r;
                    int col = n0 + nb * 16 + c;
                    int b = row >> 11, i = row & 2047, h = col >> 6, d = col & 63;
                    out[(((b << 3) + h) * 2048 + i) * 64 + d] = f2bf(acc[mt][nb][r] * scale);
                }
            }
    }
}

// ------------- Flash attention v12: pipelined dual Ptu roundtrip -------------
// Both qt softmaxes computed into registers FIRST (qt1 VALU fills qt0's DS shadow),
// then Ptu dance issued w0,r0,w1,r1 back-to-back (same-wave DS in-order: r0 sees
// pkk[0], r1 sees pkk[1]); compiler waits become lgkm(5) before PV0, lgkm(0)
// before PV1 -> ONE exposed roundtrip instead of two. Rest = R14 body.
__global__ __launch_bounds__(256, 4)
void ca_flash(const unsigned short* __restrict__ Q,
              const unsigned short* __restrict__ K,
              const unsigned short* __restrict__ VT,
              const float* __restrict__ rel_pos,
              const float* __restrict__ c_emb,
              unsigned short* __restrict__ Ob,
              const float* __restrict__ Wo,
              unsigned short* __restrict__ woT) {
    __shared__ __align__(16) char smem[38944];

    if (blockIdx.x < 64) {
        // ---- Wo transpose-cast rider ----
        float (*T)[65] = (float (*)[65])smem;     // 16.6KB < 38.9KB
        int t = blockIdx.x;
        int k0 = (t & 7) << 6, n0 = (t >> 3) << 6;
        int c = threadIdx.x & 63, r4 = threadIdx.x >> 6;
#pragma unroll
        for (int rr = 0; rr < 16; ++rr) {
            int r = r4 * 16 + rr;
            T[r][c] = Wo[(k0 + r) * 512 + n0 + c];
        }
        __syncthreads();
#pragma unroll
        for (int rr = 0; rr < 16; ++rr) {
            int r = r4 * 16 + rr;
            woT[(n0 + r) * 512 + k0 + c] = f2bf(T[c][r]);
        }
        return;
    }

    unsigned (*Ptu)[16][16] = (unsigned (*)[16][16])(smem + 32768);
    float* red = (float*)smem;                       // [3][64][41] floats
    float4* lrg4 = (float4*)(smem + 36864);          // 130 pair-entries

    int bx = blockIdx.x - 64;
    int xcd = bx & 7, slot = bx >> 3;           // slot 0..127
    int bh = xcd + ((slot >> 6) << 3);          // heads {xcd, xcd+8} per XCD
    int it = slot & 63;
    int b = bh >> 3, h = bh & 7;
    int w = threadIdx.x >> 6, lane = threadIdx.x & 63;
    int c = lane & 15, qd = lane >> 4;
    int i0 = it * 32;

    if (threadIdx.x < 130) {
        int e1 = (threadIdx.x < 129) ? threadIdx.x : 0;
        int e2 = (threadIdx.x < 129) ? ((threadIdx.x < 128) ? threadIdx.x + 1 : 128) : 0;
        float4 v;
        v.x = rel_pos[e1 * 8 + h] * QSCALE; v.y = c_emb[e1 * 8 + h];
        v.z = rel_pos[e2 * 8 + h] * QSCALE; v.w = c_emb[e2 * 8 + h];
        lrg4[threadIdx.x] = v;
    }

    const unsigned short* Qh = Q  + bh * 131072;
    const unsigned short* Kh = K  + bh * 131072;
    const unsigned short* Vh = VT + bh * 131072;
    char* kw = smem + w * 4096;                 // wave-private K slab (32 rows x 128B)
    char* vw = smem + 16384 + w * 4096;         // wave-private V slab (64 rows x 64B)

    int koff[4], voff[4];
#pragma unroll
    for (int L = 0; L < 4; ++L) {
        int kr = L * 8 + (lane >> 3);
        koff[L] = kr * 64 + (((lane & 7) ^ ((kr >> 1) & 7)) << 3);
        int vr = L * 16 + (lane >> 2);
        voff[L] = vr * 2048 + (((lane & 3) ^ ((lane >> 3) & 3)) << 3);
    }

    // prologue: stage tile t=0 (j0 = w*32): K first, then V (vmcnt(4) split)
    {
        int j0 = w * 32;
#pragma unroll
        for (int L = 0; L < 4; ++L) gld_lds16(Kh + j0 * 64 + koff[L], kw + L * 1024);
#pragma unroll
        for (int L = 0; L < 4; ++L) gld_lds16(Vh + j0 + voff[L], vw + L * 1024);
    }

    bf16x8 aq[2][2];
#pragma unroll
    for (int qt = 0; qt < 2; ++qt) {
        aq[qt][0] = ld8(Qh + (i0 + qt * 16 + c) * 64 + qd * 8);
        aq[qt][1] = ld8(Qh + (i0 + qt * 16 + c) * 64 + 32 + qd * 8);
    }

    f32x4 o2[2][4];
    float lp2[2][4];
#pragma unroll
    for (int qt = 0; qt < 2; ++qt)
#pragma unroll
        for (int db = 0; db < 4; ++db) {
            o2[qt][db] = (f32x4){0.f, 0.f, 0.f, 0.f};
            lp2[qt][db] = 0.f;
        }

    __syncthreads();   // lrg4 ready (also drains prologue stage - harmless)

    int ksw  = c & 7;          // (row>>1)&7 for K rows 2c, 2c+1
    int vsw  = (c >> 1) & 3;   // (row>>1)&3 for V rows db*16+c

    for (int t = 0; t < 16; ++t) {
        asm volatile("s_waitcnt vmcnt(4)" ::: "memory");
        __builtin_amdgcn_sched_barrier(0);
        bf16x8 bk0a = ld8((const unsigned short*)(kw + (2 * c) * 128     + (((qd)     ^ ksw) << 4)));
        bf16x8 bk0b = ld8((const unsigned short*)(kw + (2 * c) * 128     + (((qd + 4) ^ ksw) << 4)));
        bf16x8 bk1a = ld8((const unsigned short*)(kw + (2 * c + 1) * 128 + (((qd)     ^ ksw) << 4)));
        bf16x8 bk1b = ld8((const unsigned short*)(kw + (2 * c + 1) * 128 + (((qd + 4) ^ ksw) << 4)));
        asm volatile("s_waitcnt vmcnt(0)" ::: "memory");
        __builtin_amdgcn_sched_barrier(0);
        bf16x8 bv[4];
#pragma unroll
        for (int db = 0; db < 4; ++db)
            bv[db] = ld8((const unsigned short*)(vw + (db * 16 + c) * 64 + ((qd ^ vsw) << 4)));
        asm volatile("s_waitcnt lgkmcnt(0)" ::: "memory");
        __builtin_amdgcn_sched_barrier(0);
        if (t < 15) {
            int j0n = ((t + 1) * 4 + w) * 32;
#pragma unroll
            for (int L = 0; L < 4; ++L) gld_lds16(Kh + j0n * 64 + koff[L], kw + L * 1024);
#pragma unroll
            for (int L = 0; L < 4; ++L) gld_lds16(Vh + j0n + voff[L], vw + L * 1024);
        }

        int j0 = (t * 4 + w) * 32;

        // ---- hoisted QK: all 4 accumulators before any softmax ----
        f32x4 s[2][2];
        __builtin_amdgcn_s_setprio(1);
#pragma unroll
        for (int qt = 0; qt < 2; ++qt) {
            s[qt][0] = (f32x4){0.f, 0.f, 0.f, 0.f};
            s[qt][1] = (f32x4){0.f, 0.f, 0.f, 0.f};
            s[qt][0] = __builtin_amdgcn_mfma_f32_16x16x32_bf16(aq[qt][0], bk0a, s[qt][0], 0, 0, 0);
            s[qt][1] = __builtin_amdgcn_mfma_f32_16x16x32_bf16(aq[qt][0], bk1a, s[qt][1], 0, 0, 0);
            s[qt][0] = __builtin_amdgcn_mfma_f32_16x16x32_bf16(aq[qt][1], bk0b, s[qt][0], 0, 0, 0);
            s[qt][1] = __builtin_amdgcn_mfma_f32_16x16x32_bf16(aq[qt][1], bk1b, s[qt][1], 0, 0, 0);
        }
        __builtin_amdgcn_s_setprio(0);

        // ---- both softmaxes into registers (qt1 VALU fills qt0's DS shadow) ----
        unsigned pkk[2][4];
#pragma unroll
        for (int qt = 0; qt < 2; ++qt) {
            int iqt0 = i0 + qt * 16;
            int iq = iqt0 + qd * 4;
            bool lowc  = (j0 + 31 - iqt0) <= -64;   // whole tile clamps to d=0
            bool highc = (j0 - (iqt0 + 15)) >= 64;  // whole tile clamps to d=128
            if (lowc || highc) {
                int d = lowc ? 0 : 128;
                float4 gg = lrg4[d];                // wave-uniform broadcast; use .x/.y
#pragma unroll
                for (int r = 0; r < 4; ++r) {
                    float t0 = EXP2(s[qt][0][r] + gg.x);
                    float t1 = EXP2(s[qt][1][r] + gg.x);
                    lp2[qt][r] += t0 + t1;
                    pkk[qt][r] = pk2(t0 * gg.y, t1 * gg.y);
                }
            } else {
#pragma unroll
                for (int r = 0; r < 4; ++r) {
                    int i = iq + r;
                    int im1 = j0 + 2 * c - i;       // j - i for even column
                    int idx = (im1 < -64) ? 129 : ((im1 > 64 ? 64 : im1) + 64);
                    float4 g = lrg4[idx];           // (rel[d0],gate[d0],rel[d1],gate[d1])
                    float t0 = EXP2(s[qt][0][r] + g.x);
                    float t1 = EXP2(s[qt][1][r] + g.z);
                    lp2[qt][r] += t0 + t1;
                    pkk[qt][r] = pk2(t0 * g.y, t1 * g.w);
                }
            }
        }

        // ---- pipelined Ptu roundtrips: w0,r0,w1,r1 (same-wave DS in-order) ----
#pragma unroll
        for (int r = 0; r < 4; ++r) Ptu[w][qd * 4 + r][c] = pkk[0][r];
        bf16x8 ap0 = ld8((const unsigned short*)&Ptu[w][c][0] + qd * 8);
#pragma unroll
        for (int r = 0; r < 4; ++r) Ptu[w][qd * 4 + r][c] = pkk[1][r];
        bf16x8 ap1 = ld8((const unsigned short*)&Ptu[w][c][0] + qd * 8);

        __builtin_amdgcn_s_setprio(1);
#pragma unroll
        for (int db = 0; db < 4; ++db)
            o2[0][db] = __builtin_amdgcn_mfma_f32_16x16x32_bf16(ap0, bv[db], o2[0][db], 0, 0, 0);
#pragma unroll
        for (int db = 0; db < 4; ++db)
            o2[1][db] = __builtin_amdgcn_mfma_f32_16x16x32_bf16(ap1, bv[db], o2[1][db], 0, 0, 0);
        __builtin_amdgcn_s_setprio(0);
    }

    // ---- cross-wave combine (red overlaps staging slabs: barrier before reuse;
    //      last iter issued no prefetch, so no async LDS writes are in flight) ----
    __syncthreads();
    if (w > 0) {
        float* dst = red + (w - 1) * (64 * 41) + lane * 41;
#pragma unroll
        for (int qt = 0; qt < 2; ++qt)
#pragma unroll
            for (int db = 0; db < 4; ++db)
#pragma unroll
                for (int r = 0; r < 4; ++r)
                    dst[qt * 16 + db * 4 + r] = o2[qt][db][r];
#pragma unroll
        for (int qt = 0; qt < 2; ++qt)
#pragma unroll
            for (int r = 0; r < 4; ++r)
                dst[32 + qt * 4 + r] = lp2[qt][r];
    }
    __syncthreads();
    if (w == 0) {
#pragma unroll
        for (int ww = 0; ww < 3; ++ww) {
            const float* src = red + ww * (64 * 41) + lane * 41;
#pragma unroll
            for (int qt = 0; qt < 2; ++qt) {
#pragma unroll
                for (int db = 0; db < 4; ++db)
#pragma unroll
                    for (int r = 0; r < 4; ++r)
                        o2[qt][db][r] += src[qt * 16 + db * 4 + r];
#pragma unroll
                for (int r = 0; r < 4; ++r)
                    lp2[qt][r] += src[32 + qt * 4 + r];
            }
        }
#pragma unroll
        for (int qt = 0; qt < 2; ++qt)
#pragma unroll
            for (int r = 0; r < 4; ++r) {
                lp2[qt][r] += __shfl_xor(lp2[qt][r], 1);
                lp2[qt][r] += __shfl_xor(lp2[qt][r], 2);
                lp2[qt][r] += __shfl_xor(lp2[qt][r], 4);
                lp2[qt][r] += __shfl_xor(lp2[qt][r], 8);
            }
#pragma unroll
        for (int qt = 0; qt < 2; ++qt)
#pragma unroll
            for (int db = 0; db < 4; ++db)
#pragma unroll
                for (int r = 0; r < 4; ++r) {
                    int row = b * 2048 + i0 + qt * 16 + qd * 4 + r;
                    int col = h * 64 + db * 16 + c;
                    Ob[row * 512 + col] = f2bf(o2[qt][db][r] / lp2[qt][r]);
                }
    }
}

// ------------- Output GEMM v3 (R9-proven): dbuf staging, counted vmcnt, grid (64,8) --
__global__ __launch_bounds__(256, 4)
void ca_gemm_out(const unsigned short* __restrict__ A,
                 const unsigned short* __restrict__ BT,
                 const float* __restrict__ bias,
                 float* __restrict__ out) {
    __shared__ __align__(16) unsigned short Ash[2][64 * 64];
    __shared__ __align__(16) unsigned short Bsh[2][64 * 64];
    int w = threadIdx.x >> 6, lane = threadIdx.x & 63;
    int c = lane & 15, qd = lane >> 4;
    int m0 = blockIdx.x * 64 + w * 16;
    int n0 = blockIdx.y * 64;

    int lr = lane >> 3, ls = lane & 7;
    int soff = lr * 512 + ((ls ^ (lr & 7)) << 3);
    const unsigned short* Ab = A + (blockIdx.x * 64) * 512 + soff;
    const unsigned short* Bb = BT + n0 * 512 + soff;

#pragma unroll
    for (int L = 0; L < 2; ++L) {
        gld_lds16(Ab + (w * 16 + L * 8) * 512, (char*)Ash[0] + (w * 16 + L * 8) * 128);
        gld_lds16(Bb + (w * 16 + L * 8) * 512, (char*)Bsh[0] + (w * 16 + L * 8) * 128);
    }

    f32x4 acc[4];
#pragma unroll
    for (int nb = 0; nb < 4; ++nb) acc[nb] = (f32x4){0.f, 0.f, 0.f, 0.f};

    int cs = c & 7;
#pragma unroll
    for (int k = 0; k < 8; ++k) {
        int b = k & 1;
        if (k < 7) {
            int k0 = (k + 1) * 64;
#pragma unroll
            for (int L = 0; L < 2; ++L) {
                gld_lds16(Ab + k0 + (w * 16 + L * 8) * 512, (char*)Ash[b ^ 1] + (w * 16 + L * 8) * 128);
                gld_lds16(Bb + k0 + (w * 16 + L * 8) * 512, (char*)Bsh[b ^ 1] + (w * 16 + L * 8) * 128);
            }
            asm volatile("s_waitcnt vmcnt(4)" ::: "memory");
        } else {
            asm volatile("s_waitcnt vmcnt(0)" ::: "memory");
        }
        __syncthreads();
        bf16x8 a[2], bq[4][2];
#pragma unroll
        for (int kk = 0; kk < 2; ++kk)
            a[kk] = ld8((const unsigned short*)((char*)Ash[b] +
                        (w * 16 + c) * 128 + (((kk * 4 + qd) ^ cs) << 4)));
#pragma unroll
        for (int nb = 0; nb < 4; ++nb)
#pragma unroll
            for (int kk = 0; kk < 2; ++kk)
                bq[nb][kk] = ld8((const unsigned short*)((char*)Bsh[b] +
                                (nb * 16 + c) * 128 + (((kk * 4 + qd) ^ cs) << 4)));
        asm volatile("s_waitcnt lgkmcnt(0)" ::: "memory");
        __syncthreads();
#pragma unroll
        for (int kk = 0; kk < 2; ++kk)
#pragma unroll
            for (int nb = 0; nb < 4; ++nb)
                acc[nb] = __builtin_amdgcn_mfma_f32_16x16x32_bf16(a[kk], bq[nb][kk], acc[nb], 0, 0, 0);
    }
#pragma unroll
    for (int nb = 0; nb < 4; ++nb) {
#pragma unroll
        for (int r = 0; r < 4; ++r) {
            int row = m0 + qd * 4 + r;
            int col = n0 + nb * 16 + c;
            out[row * 512 + col] = acc[nb][r] + bias[col];
        }
    }
}

extern "C" void kernel_launch(void* const* d_in, const int* in_sizes, int n_in,
                              void* d_out, int out_size, void* d_ws, size_t ws_size,
                              hipStream_t stream) {
    const float* x   = (const float*)d_in[0];
    const float* Wq  = (const float*)d_in[1];
    const float* Wk  = (const float*)d_in[2];
    const float* Wv  = (const float*)d_in[3];
    const float* rel = (const float*)d_in[4];
    const float* cem = (const float*)d_in[5];
    const float* Wo  = (const float*)d_in[6];
    const float* bo  = (const float*)d_in[7];
    float* out = (float*)d_out;
    char* ws = (char*)d_ws;

    unsigned short* xb  = (unsigned short*)(ws);              // 4 MB
    unsigned short* wts = (unsigned short*)(ws + 4194304);    // 1.5 MB (Wq,Wk,Wv ^T)
    unsigned short* woT = (unsigned short*)(ws + 5767168);    // 512 KB Wo^T
    unsigned short* qkv = (unsigned short*)(ws + 6291456);    // q,k
    unsigned short* vt  = (unsigned short*)(ws + 18874368);   // 4 MB  vT bf16 [bh][DH][N]
    unsigned short* ob  = (unsigned short*)(ws + 23068672);   // 4 MB

    hipLaunchKernelGGL(ca_prep, dim3(1216), dim3(256), 0, stream, x, Wq, Wk, Wv, xb, wts);
    hipLaunchKernelGGL(ca_gemm_proj, dim3(32, 24), dim3(256), 0, stream, xb, wts, qkv, vt);
    hipLaunchKernelGGL(ca_flash, dim3(1088), dim3(256), 0, stream,
                       qkv, qkv + 2097152, vt, rel, cem, ob, Wo, woT);
    hipLaunchKernelGGL(ca_gemm_out, dim3(64, 8), dim3(256), 0, stream, ob, woT, bo, out);
}